// Round 9
// baseline (223.601 us; speedup 1.0000x reference)
//
#include <hip/hip_runtime.h>
#include <hip/hip_bf16.h>
#include <stdint.h>

#define S_LEN 2048
#define NH 16
#define NB_DELTA (2*S_LEN-1)   // 4095
#define PST 72                 // P LDS row stride in bf16 elems
#define LOG2E 1.4426950408889634f

typedef __attribute__((ext_vector_type(8))) __bf16 bf16x8;
typedef __attribute__((ext_vector_type(4))) float f32x4;

__device__ __forceinline__ unsigned short f2bf(float f){   // RNE
    union { float f; unsigned int u; } v; v.f = f;
    unsigned int u = v.u;
    return (unsigned short)((u + 0x7FFFu + ((u >> 16) & 1u)) >> 16);
}
__device__ __forceinline__ float bf2f(unsigned short u){
    union { unsigned int u; float f; } v; v.u = ((unsigned int)u) << 16;
    return v.f;
}
__device__ __forceinline__ unsigned int pkbf(float a, float b){   // HW packed cvt (RNE)
    __hip_bfloat162 h = __float22bfloat162_rn(float2{a, b});
    unsigned int u;
    __builtin_memcpy(&u, &h, 4);
    return u;
}
#if __has_builtin(__builtin_amdgcn_exp2f)
__device__ __forceinline__ float fexp2(float x){ return __builtin_amdgcn_exp2f(x); }
#else
__device__ __forceinline__ float fexp2(float x){ return __expf(x * 0.69314718056f); }
#endif

// async global->LDS, 16B per lane; LDS dest = wave-uniform base + lane*16
__device__ __forceinline__ void gload16(const void* g, void* l){
    __builtin_amdgcn_global_load_lds(
        (const __attribute__((address_space(1))) void*)(uintptr_t)g,
        (__attribute__((address_space(3))) void*)(uintptr_t)l, 16, 0, 0);
}

// ---------------- fused prep: z<4 -> transpose+cast W[z]; z==4 -> hs cast + bias table
__global__ __launch_bounds__(256) void prep_kernel(
    const float* __restrict__ hs, unsigned short* __restrict__ hsb,
    const float* __restrict__ W0, const float* __restrict__ W1,
    const float* __restrict__ W2, const float* __restrict__ W3,
    unsigned short* __restrict__ D0, unsigned short* __restrict__ D1,
    unsigned short* __restrict__ D2, unsigned short* __restrict__ D3,
    const float* __restrict__ rel_bias, float* __restrict__ biasT){
    if (blockIdx.z == 4) {
        int bi = blockIdx.y * 32 + blockIdx.x;   // 0..1023
        for (int it = 0; it < 4; it++) {
            int i = bi * 4096 + it * 1024 + threadIdx.x * 4;
            float4 f = *(const float4*)(hs + i);
            ushort4 o;
            o.x = f2bf(f.x); o.y = f2bf(f.y); o.z = f2bf(f.z); o.w = f2bf(f.w);
            *(ushort4*)(hsb + i) = o;
        }
        if (bi < 16) {
            int t = bi * 256 + threadIdx.x;
            if (t < NB_DELTA) {
                int delta = t - (S_LEN - 1);          // j - i
                int bucket = (delta > 0) ? 16 : 0;
                int a = delta < 0 ? -delta : delta;
                int b;
                if (a < 8) b = a;
                else {
                    int bl = 33 - __builtin_clz(a * a);   // 8 + floor(2*log2(a/8)), exact
                    b = bl < 15 ? bl : 15;
                }
                bucket += b;
                for (int h = 0; h < NH; h++)
                    biasT[h * NB_DELTA + t] = rel_bias[bucket * NH + h];
            }
        }
        return;
    }
    const float* src; unsigned short* dst;
    switch (blockIdx.z) {
        case 0: src = W0; dst = D0; break;
        case 1: src = W1; dst = D1; break;
        case 2: src = W2; dst = D2; break;
        default: src = W3; dst = D3; break;
    }
    __shared__ float tile[32][33];
    int bx = blockIdx.x, by = blockIdx.y;
    int tx = threadIdx.x & 31, ty = threadIdx.x >> 5;
    for (int i = 0; i < 4; i++)
        tile[ty + 8*i][tx] = src[(size_t)(by*32 + ty + 8*i) * 1024 + bx*32 + tx];
    __syncthreads();
    for (int i = 0; i < 4; i++)
        dst[(size_t)(bx*32 + ty + 8*i) * 1024 + by*32 + tx] = f2bf(tile[tx][ty + 8*i]);
}

// ---------------- bf16 MFMA GEMM, BK=64, async staging, XOR-granule-swizzled LDS.
// MODE 0: fp32 row-major into C0; MODE 1: bf16 row-major into C1, with cols<1024
// (the Q block) pre-scaled by log2e for the exp2 softmax path.
template<int MODE, int BM>
__global__ __launch_bounds__(256) void gemm_bt_kernel(const unsigned short* __restrict__ A,
                                                      const unsigned short* __restrict__ BT,
                                                      float* __restrict__ C0,
                                                      unsigned short* __restrict__ C1,
                                                      int Kdim, int ldc){
    constexpr int IT = BM / 32;     // m-tiles per wave
    __shared__ __align__(16) unsigned short As[BM * 64];
    __shared__ __align__(16) unsigned short Bs[128 * 64];
    const int t = threadIdx.x;
    const int wave = t >> 6, lane = t & 63;
    const int quad = lane >> 4, l16 = lane & 15;
    const int wm = (wave >> 1) * (BM / 2), wn = (wave & 1) * 64;
    const size_t row0 = (size_t)blockIdx.y * BM, col0 = (size_t)blockIdx.x * 128;

    const int srow8 = lane >> 3;                 // 0..7: row within the wave's 8-row group
    const int gg = (lane & 7) ^ srow8;           // fetch-side granule remap
    const unsigned short* gA = A  + (row0 + wave * 8 + srow8) * (size_t)Kdim + gg * 8;
    const unsigned short* gB = BT + (col0 + wave * 8 + srow8) * (size_t)Kdim + gg * 8;

    f32x4 acc[IT][4] = {};

    for (int kt = 0; kt < Kdim; kt += 64) {
        for (int p = 0; p < BM / 32; p++)
            gload16(gA + (size_t)(p * 32) * Kdim + kt, &As[(p * 32 + wave * 8) * 64]);
        for (int p = 0; p < 4; p++)
            gload16(gB + (size_t)(p * 32) * Kdim + kt, &Bs[(p * 32 + wave * 8) * 64]);
        __syncthreads();
        bf16x8 a[2][IT], b[2][4];
        for (int ks = 0; ks < 2; ks++) {
            for (int i = 0; i < IT; i++)
                a[ks][i] = *(const bf16x8*)(&As[(wm + i*16 + l16) * 64 + (((ks*4 + quad) ^ (l16 & 7)) * 8)]);
            for (int j = 0; j < 4; j++)
                b[ks][j] = *(const bf16x8*)(&Bs[(wn + j*16 + l16) * 64 + (((ks*4 + quad) ^ (l16 & 7)) * 8)]);
        }
        for (int ks = 0; ks < 2; ks++)
            for (int i = 0; i < IT; i++)
                for (int j = 0; j < 4; j++)
                    acc[i][j] = __builtin_amdgcn_mfma_f32_16x16x32_bf16(a[ks][i], b[ks][j], acc[i][j], 0, 0, 0);
        __syncthreads();
    }
    // C/D layout: col = lane&15, row = quad*4 + reg
    for (int i = 0; i < IT; i++)
        for (int j = 0; j < 4; j++) {
            size_t r0 = row0 + wm + i*16 + quad*4;
            size_t c  = col0 + wn + j*16 + l16;
            if (MODE == 0) {
                for (int r = 0; r < 4; r++)
                    C0[(r0 + r) * ldc + c] = acc[i][j][r];
            } else {
                float qs = (c < 1024) ? LOG2E : 1.0f;   // pre-scale Q for exp2 softmax
                for (int r = 0; r < 4; r++)
                    C1[(r0 + r) * ldc + c] = f2bf(acc[i][j][r] * qs);
            }
        }
}

// ---------------- V transpose: Vt[b*1024 + v][s] = qkv[b*2048 + s][2048 + v]
__global__ __launch_bounds__(256) void vtrans_kernel(const unsigned short* __restrict__ qkv,
                                                     unsigned short* __restrict__ vt){
    __shared__ unsigned short tile[64][72];
    const int v0 = blockIdx.x * 64, s0 = blockIdx.y * 64, b = blockIdx.z;
    const int tx = threadIdx.x & 7, ty = threadIdx.x >> 3;   // ty 0..31
    for (int i = 0; i < 2; i++)
        *(int4*)&tile[ty + 32*i][tx * 8] =
            *(const int4*)(qkv + (size_t)(b * 2048 + s0 + ty + 32*i) * 3072 + 2048 + v0 + tx * 8);
    __syncthreads();
    for (int i = 0; i < 2; i++) {
        int v = ty + 32*i;
        int sl = tx * 8;
        ushort4 o0, o1;
        o0.x = tile[sl+0][v]; o0.y = tile[sl+1][v]; o0.z = tile[sl+2][v]; o0.w = tile[sl+3][v];
        o1.x = tile[sl+4][v]; o1.y = tile[sl+5][v]; o1.z = tile[sl+6][v]; o1.w = tile[sl+7][v];
        unsigned short* dst = vt + (size_t)(b * 1024 + v0 + v) * 2048 + s0 + sl;
        *(ushort4*)dst = o0; *(ushort4*)(dst + 4) = o1;
    }
}

// ---------------- MFMA flash attention v8: j-split waves (64q x 32j), exp2 softmax,
// constant-bias fast path, split-S x2, swizzled async K/V staging.
// grid (S/128, NH, B*2); wave w: qh = w&1 (q-half of 128), jh = w>>1 (j-half of 64).
__global__ __launch_bounds__(256, 3) void flash8_kernel(
    const unsigned short* __restrict__ qkv,
    const unsigned short* __restrict__ vt,
    const float* __restrict__ biasT,
    const float* __restrict__ rel_bias,
    unsigned short* __restrict__ ctxpb,   // [2][4096][1024] bf16 unnormalized
    float* __restrict__ rsbuf)            // [2][4096][16]  fp32 row sums
{
    const int qt = blockIdx.x, h = blockIdx.y;
    const int b = blockIdx.z >> 1, ck = blockIdx.z & 1;
    const int kt0 = ck << 10;
    const int t = threadIdx.x;
    const int w = t >> 6, lane = t & 63, quad = lane >> 4, l16 = lane & 15;
    const int qh = w & 1, jh = w >> 1;
    const int q0 = qt * 128;

    __shared__ __align__(16) unsigned short SMEM[18272];
    unsigned short* Ks = SMEM;              // 64x64 swizzled  (shorts 0..4096)
    unsigned short* Vs = SMEM + 4096;       // 64x64 swizzled  (4096..8192)
    unsigned short* Pb = SMEM + 8192;       // 128 x PST       (8192..17408); Q scratch in prologue
    float* bias_s = (float*)(SMEM + 17408); // 192 floats

    // per-head constant-bias values (|delta|>=128 -> bucket 15 / 31), pre-scaled
    const float b15 = (rel_bias[15 * NH + h] - 16.f) * LOG2E;
    const float b31 = (rel_bias[31 * NH + h] - 16.f) * LOG2E;

    // stage Q (128 x 64 bf16) into Pb scratch
    for (int s = 0; s < 4; s++) {
        int g = t + s * 256;
        int r = g >> 3, c = (g & 7) * 8;
        *(int4*)&Pb[r * PST + c] =
            *(const int4*)(qkv + (size_t)(b * S_LEN + q0 + r) * 3072 + h * 64 + c);
    }
    __syncthreads();
    bf16x8 qb[2][4];   // [ks][nt]; q = qh*64 + nt*16 + l16 (already log2e-scaled)
    for (int nt = 0; nt < 4; nt++)
        for (int ks = 0; ks < 2; ks++)
            qb[ks][nt] = *(const bf16x8*)&Pb[(qh * 64 + nt * 16 + l16) * PST + ks * 32 + quad * 8];

    float rsum[4] = {0.f, 0.f, 0.f, 0.f};
    f32x4 ctx[4][4] = {};   // ctx^T partial: [d-tile nd][q-tile nt], this wave's jh half

    const float* biasRow = biasT + h * NB_DELTA + 2047;

    const int srow8 = lane >> 3;
    const int gg = (lane & 7) ^ srow8;
    const int swz = ((l16 & 7) * 8);

    for (int kt = kt0; kt < kt0 + 1024; kt += 64) {
        const int off = kt - q0;
        const bool cst = (off >= 255) || (off <= -191);   // whole tile |delta|>=128
        __syncthreads();
        {
            const unsigned short* kb = qkv + (size_t)(b * S_LEN + kt + w * 8 + srow8) * 3072 + 1024 + h * 64 + gg * 8;
            const unsigned short* vb = vt + (size_t)(b * 1024 + h * 64 + w * 8 + srow8) * 2048 + kt + gg * 8;
            gload16(kb,                     &Ks[(w * 8) * 64]);
            gload16(kb + (size_t)32 * 3072, &Ks[(32 + w * 8) * 64]);
            gload16(vb,                     &Vs[(w * 8) * 64]);
            gload16(vb + (size_t)32 * 2048, &Vs[(32 + w * 8) * 64]);
            if (!cst && t < 192) bias_s[t] = (biasRow[off - 127 + t] - 16.f) * LOG2E;
        }
        __syncthreads();

        // S^T = K Q^T over this wave's 32 j: 2 nb x 2 ks reads, each feeds 4 q-tiles
        f32x4 st[2][4] = {};
        for (int ks = 0; ks < 2; ks++)
            for (int nb = 0; nb < 2; nb++) {
                bf16x8 ka = *(const bf16x8*)&Ks[(jh * 32 + nb * 16 + l16) * 64 + (((ks * 4 + quad) * 8) ^ swz)];
                for (int nt = 0; nt < 4; nt++)
                    st[nb][nt] = __builtin_amdgcn_mfma_f32_16x16x32_bf16(ka, qb[ks][nt], st[nb][nt], 0, 0, 0);
            }
        // exp2 softmax (scores already scaled by log2e), pack P^T
        const float bc = (off > 0) ? b31 : b15;
        for (int nt = 0; nt < 4; nt++) {
            const int ib = jh * 32 + quad * 4 + 127 - qh * 64 - nt * 16 - l16;
            float rs = 0.f;
            for (int nb = 0; nb < 2; nb++) {
                float e0, e1, e2, e3;
                if (cst) {
                    e0 = fexp2(st[nb][nt][0] + bc);
                    e1 = fexp2(st[nb][nt][1] + bc);
                    e2 = fexp2(st[nb][nt][2] + bc);
                    e3 = fexp2(st[nb][nt][3] + bc);
                } else {
                    e0 = fexp2(st[nb][nt][0] + bias_s[ib + nb * 16 + 0]);
                    e1 = fexp2(st[nb][nt][1] + bias_s[ib + nb * 16 + 1]);
                    e2 = fexp2(st[nb][nt][2] + bias_s[ib + nb * 16 + 2]);
                    e3 = fexp2(st[nb][nt][3] + bias_s[ib + nb * 16 + 3]);
                }
                rs += (e0 + e1) + (e2 + e3);
                uint2 pk; pk.x = pkbf(e0, e1); pk.y = pkbf(e2, e3);
                *(uint2*)&Pb[(qh * 64 + nt * 16 + l16) * PST + jh * 32 + nb * 16 + quad * 4] = pk;
            }
            rsum[nt] += rs;
        }
        // ctx^T += Vt . P^T over this wave's 32 j
        bf16x8 pb[4];
        for (int nt = 0; nt < 4; nt++)
            pb[nt] = *(const bf16x8*)&Pb[(qh * 64 + nt * 16 + l16) * PST + jh * 32 + quad * 8];
        for (int nd = 0; nd < 4; nd++) {
            bf16x8 va = *(const bf16x8*)&Vs[(nd * 16 + l16) * 64 + (((jh * 4 + quad) * 8) ^ swz)];
            for (int nt = 0; nt < 4; nt++)
                ctx[nd][nt] = __builtin_amdgcn_mfma_f32_16x16x32_bf16(va, pb[nt], ctx[nd][nt], 0, 0, 0);
        }
    }
    // epilogue: cross-wave (jh) reduction of ctx and rsum via LDS scratch
    __syncthreads();
    float* fscr = (float*)SMEM;   // 8192 floats ctx + 128 floats rsum = 33 KB < 36.5 KB
    float rsq[4];
    for (int nt = 0; nt < 4; nt++) {
        float rs = rsum[nt];
        rs += __shfl_xor(rs, 16, 64);
        rs += __shfl_xor(rs, 32, 64);
        rsq[nt] = rs;
    }
    if (jh == 1) {
        float* dst = fscr + (qh << 12) + lane * 4;
        for (int nd = 0; nd < 4; nd++)
            for (int nt = 0; nt < 4; nt++)
                *(f32x4*)(dst + (nd * 4 + nt) * 256) = ctx[nd][nt];
        if (quad == 0)
            for (int nt = 0; nt < 4; nt++)
                fscr[8192 + (qh << 6) + nt * 16 + l16] = rsq[nt];
    }
    __syncthreads();
    if (jh == 0) {
        float* src = fscr + (qh << 12) + lane * 4;
        for (int nd = 0; nd < 4; nd++)
            for (int nt = 0; nt < 4; nt++)
                ctx[nd][nt] += *(const f32x4*)(src + (nd * 4 + nt) * 256);
        unsigned short* cp = ctxpb + (size_t)ck * 4096 * 1024;
        for (int nt = 0; nt < 4; nt++) {
            float rst = rsq[nt] + fscr[8192 + (qh << 6) + nt * 16 + l16];
            int row = b * S_LEN + q0 + qh * 64 + nt * 16 + l16;
            if (quad == 0) rsbuf[((size_t)ck * 4096 + row) * 16 + h] = rst;
            for (int nd = 0; nd < 4; nd++) {
                uint2 pk;
                pk.x = pkbf(ctx[nd][nt][0], ctx[nd][nt][1]);
                pk.y = pkbf(ctx[nd][nt][2], ctx[nd][nt][3]);
                *(uint2*)&cp[(size_t)row * 1024 + h * 64 + nd * 16 + quad * 4] = pk;
            }
        }
    }
}

// ---------------- combine: ctx_bf16 = (ctx0 + ctx1) / (l0 + l1)
__global__ __launch_bounds__(256) void combine_kernel(const unsigned short* __restrict__ ctxpb,
                                                      const float* __restrict__ rsbuf,
                                                      unsigned short* __restrict__ ctxb){
    int e = blockIdx.x * 256 + threadIdx.x;     // one ushort4 per thread
    int row = e >> 8;
    int c4 = (e & 255) * 4;
    int h = c4 >> 6;
    float l = rsbuf[(size_t)row * 16 + h] + rsbuf[((size_t)4096 + row) * 16 + h];
    ushort4 a  = *(const ushort4*)&ctxpb[(size_t)row * 1024 + c4];
    ushort4 b2 = *(const ushort4*)&ctxpb[(size_t)4096 * 1024 + (size_t)row * 1024 + c4];
    float inv = 1.f / l;
    uint2 o;
    o.x = pkbf((bf2f(a.x) + bf2f(b2.x)) * inv, (bf2f(a.y) + bf2f(b2.y)) * inv);
    o.y = pkbf((bf2f(a.z) + bf2f(b2.z)) * inv, (bf2f(a.w) + bf2f(b2.w)) * inv);
    *(uint2*)&ctxb[(size_t)row * 1024 + c4] = o;
}

extern "C" void kernel_launch(void* const* d_in, const int* in_sizes, int n_in,
                              void* d_out, int out_size, void* d_ws, size_t ws_size,
                              hipStream_t stream) {
    const float* hs       = (const float*)d_in[0];
    const float* Wq       = (const float*)d_in[1];
    const float* Wk       = (const float*)d_in[2];
    const float* Wv       = (const float*)d_in[3];
    const float* Wo       = (const float*)d_in[4];
    const float* rel_bias = (const float*)d_in[5];
    float* out = (float*)d_out;

    char* ws = (char*)d_ws;
    float* biasT          = (float*)ws;           ws += 262144;      // 16*4095*4 (+pad)
    unsigned short* hsb   = (unsigned short*)ws;  ws += 8388608;     // 4096x1024 bf16
    unsigned short* WT    = (unsigned short*)ws;  ws += 6291456;     // [Wq^T|Wk^T|Wv^T] 3072x1024
    unsigned short* WoT   = (unsigned short*)ws;  ws += 2097152;     // 1024x1024 bf16
    unsigned short* qkvb  = (unsigned short*)ws;  ws += 25165824;    // 4096x3072 bf16 (Q|K|V)
    unsigned short* Vtg   = (unsigned short*)ws;  ws += 8388608;     // 2048x2048 bf16
    unsigned short* ctxb  = (unsigned short*)ws;  ws += 8388608;     // 4096x1024 bf16
    unsigned short* ctxpb = (unsigned short*)ws;  ws += 16777216;    // 2 x 4096x1024 bf16
    float* rsbuf          = (float*)ws;                              // 2 x 4096x16 fp32

    prep_kernel<<<dim3(32, 32, 5), 256, 0, stream>>>(
        hs, hsb, Wq, Wk, Wv, Wo,
        WT, WT + 1024 * 1024, WT + 2 * 1024 * 1024, WoT, rel_bias, biasT);

    // Q|K|V projection, row-major -> qkvb[4096][3072] (Q block pre-scaled by log2e)
    gemm_bt_kernel<1, 128><<<dim3(24, 32), 256, 0, stream>>>(hsb, WT, nullptr, qkvb, 1024, 3072);
    // V transpose -> Vt[b*1024 + d][2048]
    vtrans_kernel<<<dim3(16, 32, 2), 256, 0, stream>>>(qkvb, Vtg);
    // attention, split-S x2
    flash8_kernel<<<dim3(S_LEN / 128, NH, 4), 256, 0, stream>>>(qkvb, Vtg, biasT, rel_bias, ctxpb, rsbuf);
    // combine partials -> bf16 ctx
    combine_kernel<<<4096, 256, 0, stream>>>(ctxpb, rsbuf, ctxb);
    // output projection -> fp32 (BM=64: 512 blocks, 2/CU)
    gemm_bt_kernel<0, 64><<<dim3(8, 64), 256, 0, stream>>>(ctxb, WoT, out, nullptr, 1024, 1024);
}

// Round 10
// 203.011 us; speedup vs baseline: 1.1014x; 1.1014x over previous
//
#include <hip/hip_runtime.h>
#include <hip/hip_bf16.h>
#include <stdint.h>

#define S_LEN 2048
#define NH 16
#define NB_DELTA (2*S_LEN-1)   // 4095
#define PST 72                 // P LDS row stride in bf16 elems
#define LOG2E 1.4426950408889634f

typedef __attribute__((ext_vector_type(8))) __bf16 bf16x8;
typedef __attribute__((ext_vector_type(4))) float f32x4;

__device__ __forceinline__ unsigned short f2bf(float f){   // RNE
    union { float f; unsigned int u; } v; v.f = f;
    unsigned int u = v.u;
    return (unsigned short)((u + 0x7FFFu + ((u >> 16) & 1u)) >> 16);
}
__device__ __forceinline__ float bf2f(unsigned short u){
    union { unsigned int u; float f; } v; v.u = ((unsigned int)u) << 16;
    return v.f;
}
__device__ __forceinline__ unsigned int pkbf(float a, float b){   // HW packed cvt (RNE)
    __hip_bfloat162 h = __float22bfloat162_rn(float2{a, b});
    unsigned int u;
    __builtin_memcpy(&u, &h, 4);
    return u;
}
#if __has_builtin(__builtin_amdgcn_exp2f)
__device__ __forceinline__ float fexp2(float x){ return __builtin_amdgcn_exp2f(x); }
#else
__device__ __forceinline__ float fexp2(float x){ return __expf(x * 0.69314718056f); }
#endif

// async global->LDS, 16B per lane; LDS dest = wave-uniform base + lane*16
__device__ __forceinline__ void gload16(const void* g, void* l){
    __builtin_amdgcn_global_load_lds(
        (const __attribute__((address_space(1))) void*)(uintptr_t)g,
        (__attribute__((address_space(3))) void*)(uintptr_t)l, 16, 0, 0);
}

// ---------------- fused prep: z<4 -> transpose+cast W[z]; z==4 -> hs cast + bias table
__global__ __launch_bounds__(256) void prep_kernel(
    const float* __restrict__ hs, unsigned short* __restrict__ hsb,
    const float* __restrict__ W0, const float* __restrict__ W1,
    const float* __restrict__ W2, const float* __restrict__ W3,
    unsigned short* __restrict__ D0, unsigned short* __restrict__ D1,
    unsigned short* __restrict__ D2, unsigned short* __restrict__ D3,
    const float* __restrict__ rel_bias, float* __restrict__ biasT){
    if (blockIdx.z == 4) {
        int bi = blockIdx.y * 32 + blockIdx.x;   // 0..1023
        for (int it = 0; it < 4; it++) {
            int i = bi * 4096 + it * 1024 + threadIdx.x * 4;
            float4 f = *(const float4*)(hs + i);
            ushort4 o;
            o.x = f2bf(f.x); o.y = f2bf(f.y); o.z = f2bf(f.z); o.w = f2bf(f.w);
            *(ushort4*)(hsb + i) = o;
        }
        if (bi < 16) {
            int t = bi * 256 + threadIdx.x;
            if (t < NB_DELTA) {
                int delta = t - (S_LEN - 1);          // j - i
                int bucket = (delta > 0) ? 16 : 0;
                int a = delta < 0 ? -delta : delta;
                int b;
                if (a < 8) b = a;
                else {
                    int bl = 33 - __builtin_clz(a * a);   // 8 + floor(2*log2(a/8)), exact
                    b = bl < 15 ? bl : 15;
                }
                bucket += b;
                for (int h = 0; h < NH; h++)
                    biasT[h * NB_DELTA + t] = rel_bias[bucket * NH + h];
            }
        }
        return;
    }
    const float* src; unsigned short* dst;
    switch (blockIdx.z) {
        case 0: src = W0; dst = D0; break;
        case 1: src = W1; dst = D1; break;
        case 2: src = W2; dst = D2; break;
        default: src = W3; dst = D3; break;
    }
    __shared__ float tile[32][33];
    int bx = blockIdx.x, by = blockIdx.y;
    int tx = threadIdx.x & 31, ty = threadIdx.x >> 5;
    for (int i = 0; i < 4; i++)
        tile[ty + 8*i][tx] = src[(size_t)(by*32 + ty + 8*i) * 1024 + bx*32 + tx];
    __syncthreads();
    for (int i = 0; i < 4; i++)
        dst[(size_t)(bx*32 + ty + 8*i) * 1024 + by*32 + tx] = f2bf(tile[tx][ty + 8*i]);
}

// ---------------- bf16 MFMA GEMM, BK=64, async staging, XOR-granule-swizzled LDS.
// MODE 0: fp32 row-major into C0; MODE 1: bf16 row-major into C1, with cols<1024
// (the Q block) pre-scaled by log2e for the exp2 softmax path.
template<int MODE, int BM>
__global__ __launch_bounds__(256) void gemm_bt_kernel(const unsigned short* __restrict__ A,
                                                      const unsigned short* __restrict__ BT,
                                                      float* __restrict__ C0,
                                                      unsigned short* __restrict__ C1,
                                                      int Kdim, int ldc){
    constexpr int IT = BM / 32;     // m-tiles per wave
    __shared__ __align__(16) unsigned short As[BM * 64];
    __shared__ __align__(16) unsigned short Bs[128 * 64];
    const int t = threadIdx.x;
    const int wave = t >> 6, lane = t & 63;
    const int quad = lane >> 4, l16 = lane & 15;
    const int wm = (wave >> 1) * (BM / 2), wn = (wave & 1) * 64;
    const size_t row0 = (size_t)blockIdx.y * BM, col0 = (size_t)blockIdx.x * 128;

    const int srow8 = lane >> 3;                 // 0..7: row within the wave's 8-row group
    const int gg = (lane & 7) ^ srow8;           // fetch-side granule remap
    const unsigned short* gA = A  + (row0 + wave * 8 + srow8) * (size_t)Kdim + gg * 8;
    const unsigned short* gB = BT + (col0 + wave * 8 + srow8) * (size_t)Kdim + gg * 8;

    f32x4 acc[IT][4] = {};

    for (int kt = 0; kt < Kdim; kt += 64) {
        for (int p = 0; p < BM / 32; p++)
            gload16(gA + (size_t)(p * 32) * Kdim + kt, &As[(p * 32 + wave * 8) * 64]);
        for (int p = 0; p < 4; p++)
            gload16(gB + (size_t)(p * 32) * Kdim + kt, &Bs[(p * 32 + wave * 8) * 64]);
        __syncthreads();
        bf16x8 a[2][IT], b[2][4];
        for (int ks = 0; ks < 2; ks++) {
            for (int i = 0; i < IT; i++)
                a[ks][i] = *(const bf16x8*)(&As[(wm + i*16 + l16) * 64 + (((ks*4 + quad) ^ (l16 & 7)) * 8)]);
            for (int j = 0; j < 4; j++)
                b[ks][j] = *(const bf16x8*)(&Bs[(wn + j*16 + l16) * 64 + (((ks*4 + quad) ^ (l16 & 7)) * 8)]);
        }
        for (int ks = 0; ks < 2; ks++)
            for (int i = 0; i < IT; i++)
                for (int j = 0; j < 4; j++)
                    acc[i][j] = __builtin_amdgcn_mfma_f32_16x16x32_bf16(a[ks][i], b[ks][j], acc[i][j], 0, 0, 0);
        __syncthreads();
    }
    // C/D layout: col = lane&15, row = quad*4 + reg
    for (int i = 0; i < IT; i++)
        for (int j = 0; j < 4; j++) {
            size_t r0 = row0 + wm + i*16 + quad*4;
            size_t c  = col0 + wn + j*16 + l16;
            if (MODE == 0) {
                for (int r = 0; r < 4; r++)
                    C0[(r0 + r) * ldc + c] = acc[i][j][r];
            } else {
                float qs = (c < 1024) ? LOG2E : 1.0f;   // pre-scale Q for exp2 softmax
                for (int r = 0; r < 4; r++)
                    C1[(r0 + r) * ldc + c] = f2bf(acc[i][j][r] * qs);
            }
        }
}

// ---------------- V transpose: Vt[b*1024 + v][s] = qkv[b*2048 + s][2048 + v]
__global__ __launch_bounds__(256) void vtrans_kernel(const unsigned short* __restrict__ qkv,
                                                     unsigned short* __restrict__ vt){
    __shared__ unsigned short tile[64][72];
    const int v0 = blockIdx.x * 64, s0 = blockIdx.y * 64, b = blockIdx.z;
    const int tx = threadIdx.x & 7, ty = threadIdx.x >> 3;   // ty 0..31
    for (int i = 0; i < 2; i++)
        *(int4*)&tile[ty + 32*i][tx * 8] =
            *(const int4*)(qkv + (size_t)(b * 2048 + s0 + ty + 32*i) * 3072 + 2048 + v0 + tx * 8);
    __syncthreads();
    for (int i = 0; i < 2; i++) {
        int v = ty + 32*i;
        int sl = tx * 8;
        ushort4 o0, o1;
        o0.x = tile[sl+0][v]; o0.y = tile[sl+1][v]; o0.z = tile[sl+2][v]; o0.w = tile[sl+3][v];
        o1.x = tile[sl+4][v]; o1.y = tile[sl+5][v]; o1.z = tile[sl+6][v]; o1.w = tile[sl+7][v];
        unsigned short* dst = vt + (size_t)(b * 1024 + v0 + v) * 2048 + s0 + sl;
        *(ushort4*)dst = o0; *(ushort4*)(dst + 4) = o1;
    }
}

// ---------------- MFMA flash attention v10 = flash7 structure (4 waves x 32q x 64j)
// + constant-bias fast path + exp2 softmax (Q pre-scaled) + packed bf16 converts.
// split-S x2, swizzled async K/V staging.  grid (S/128, NH, B*2).
__global__ __launch_bounds__(256, 4) void flash10_kernel(
    const unsigned short* __restrict__ qkv,
    const unsigned short* __restrict__ vt,
    const float* __restrict__ biasT,
    const float* __restrict__ rel_bias,
    unsigned short* __restrict__ ctxpb,   // [2][4096][1024] bf16 unnormalized
    float* __restrict__ rsbuf)            // [2][4096][16]  fp32 row sums
{
    const int qt = blockIdx.x, h = blockIdx.y;
    const int b = blockIdx.z >> 1, ck = blockIdx.z & 1;
    const int kt0 = ck << 10;
    const int t = threadIdx.x;
    const int w = t >> 6, lane = t & 63, quad = lane >> 4, l16 = lane & 15;
    const int q0 = qt * 128;

    __shared__ __align__(16) unsigned short Ks[64 * 64];     // [token j][dim], swizzled
    __shared__ __align__(16) unsigned short Vs[64 * 64];     // [dim d][token], swizzled
    __shared__ __align__(16) unsigned short Pb[128 * PST];   // P^T; Q scratch in prologue
    __shared__ float bias_s[192];

    // per-head constant-bias values (|delta|>=128 -> bucket 15 / 31), log2e-scaled, -16 shift
    const float b15 = (rel_bias[15 * NH + h] - 16.f) * LOG2E;
    const float b31 = (rel_bias[31 * NH + h] - 16.f) * LOG2E;

    // stage Q (128 x 64 bf16) into Pb scratch (Q already log2e-scaled by the GEMM)
    for (int s = 0; s < 4; s++) {
        int g = t + s * 256;
        int r = g >> 3, c = (g & 7) * 8;
        *(int4*)&Pb[r * PST + c] =
            *(const int4*)(qkv + (size_t)(b * S_LEN + q0 + r) * 3072 + h * 64 + c);
    }
    __syncthreads();
    bf16x8 qb[2][2];   // [ks][nt]
    for (int nt = 0; nt < 2; nt++)
        for (int ks = 0; ks < 2; ks++)
            qb[ks][nt] = *(const bf16x8*)&Pb[(w * 32 + nt * 16 + l16) * PST + ks * 32 + quad * 8];

    float rsum[2] = {0.f, 0.f};
    f32x4 ctx[4][2] = {};   // ctx^T: [d-tile nd][n-tile nt]

    const float* biasRow = biasT + h * NB_DELTA + 2047;

    const int srow8 = lane >> 3;
    const int gg = (lane & 7) ^ srow8;
    const int swz = ((l16 & 7) * 8);

    for (int kt = kt0; kt < kt0 + 1024; kt += 64) {
        const int off = kt - q0;
        const bool cst = (off >= 255) || (off <= -191);   // whole tile |delta|>=128
        __syncthreads();
        {
            const unsigned short* kb = qkv + (size_t)(b * S_LEN + kt + w * 8 + srow8) * 3072 + 1024 + h * 64 + gg * 8;
            const unsigned short* vb = vt + (size_t)(b * 1024 + h * 64 + w * 8 + srow8) * 2048 + kt + gg * 8;
            gload16(kb,                     &Ks[(w * 8) * 64]);
            gload16(kb + (size_t)32 * 3072, &Ks[(32 + w * 8) * 64]);
            gload16(vb,                     &Vs[(w * 8) * 64]);
            gload16(vb + (size_t)32 * 2048, &Vs[(32 + w * 8) * 64]);
            if (!cst && t < 192) bias_s[t] = (biasRow[off - 127 + t] - 16.f) * LOG2E;
        }
        __syncthreads();

        // S^T = K Q^T : A = K rows (m=j), B = Q (n=q); each ka feeds both n-tiles
        f32x4 st[4][2] = {};
        for (int ks = 0; ks < 2; ks++)
            for (int nb = 0; nb < 4; nb++) {
                bf16x8 ka = *(const bf16x8*)&Ks[(nb * 16 + l16) * 64 + (((ks * 4 + quad) * 8) ^ swz)];
                st[nb][0] = __builtin_amdgcn_mfma_f32_16x16x32_bf16(ka, qb[ks][0], st[nb][0], 0, 0, 0);
                st[nb][1] = __builtin_amdgcn_mfma_f32_16x16x32_bf16(ka, qb[ks][1], st[nb][1], 0, 0, 0);
            }
        // exp2 softmax (scores already log2e-scaled), pack P^T
        const float bc = (off > 0) ? b31 : b15;
        for (int nt = 0; nt < 2; nt++) {
            const int ib = quad * 4 + 127 - w * 32 - nt * 16 - l16;
            float rs = 0.f;
            for (int nb = 0; nb < 4; nb++) {
                float e0, e1, e2, e3;
                if (cst) {
                    e0 = fexp2(st[nb][nt][0] + bc);
                    e1 = fexp2(st[nb][nt][1] + bc);
                    e2 = fexp2(st[nb][nt][2] + bc);
                    e3 = fexp2(st[nb][nt][3] + bc);
                } else {
                    e0 = fexp2(st[nb][nt][0] + bias_s[ib + nb * 16 + 0]);
                    e1 = fexp2(st[nb][nt][1] + bias_s[ib + nb * 16 + 1]);
                    e2 = fexp2(st[nb][nt][2] + bias_s[ib + nb * 16 + 2]);
                    e3 = fexp2(st[nb][nt][3] + bias_s[ib + nb * 16 + 3]);
                }
                rs += (e0 + e1) + (e2 + e3);
                uint2 pk; pk.x = pkbf(e0, e1); pk.y = pkbf(e2, e3);
                *(uint2*)&Pb[(w * 32 + nt * 16 + l16) * PST + nb * 16 + quad * 4] = pk;
            }
            rsum[nt] += rs;
        }
        // ctx^T += Vt . P^T : each va feeds both n-tiles
        for (int ks = 0; ks < 2; ks++) {
            bf16x8 pb0 = *(const bf16x8*)&Pb[(w * 32 + l16) * PST + ks * 32 + quad * 8];
            bf16x8 pb1 = *(const bf16x8*)&Pb[(w * 32 + 16 + l16) * PST + ks * 32 + quad * 8];
            for (int nd = 0; nd < 4; nd++) {
                bf16x8 va = *(const bf16x8*)&Vs[(nd * 16 + l16) * 64 + (((ks * 4 + quad) * 8) ^ swz)];
                ctx[nd][0] = __builtin_amdgcn_mfma_f32_16x16x32_bf16(va, pb0, ctx[nd][0], 0, 0, 0);
                ctx[nd][1] = __builtin_amdgcn_mfma_f32_16x16x32_bf16(va, pb1, ctx[nd][1], 0, 0, 0);
            }
        }
    }
    // epilogue: store UNNORMALIZED bf16 partials + fp32 row sums
    unsigned short* cp = ctxpb + (size_t)ck * 4096 * 1024;
    for (int nt = 0; nt < 2; nt++) {
        float rs = rsum[nt];
        rs += __shfl_xor(rs, 16, 64);
        rs += __shfl_xor(rs, 32, 64);
        int row = b * S_LEN + q0 + w * 32 + nt * 16 + l16;
        if (quad == 0) rsbuf[((size_t)ck * 4096 + row) * 16 + h] = rs;
        for (int nd = 0; nd < 4; nd++) {
            uint2 pk;
            pk.x = pkbf(ctx[nd][nt][0], ctx[nd][nt][1]);
            pk.y = pkbf(ctx[nd][nt][2], ctx[nd][nt][3]);
            *(uint2*)&cp[(size_t)row * 1024 + h * 64 + nd * 16 + quad * 4] = pk;
        }
    }
}

// ---------------- combine: ctx_bf16 = (ctx0 + ctx1) / (l0 + l1)
__global__ __launch_bounds__(256) void combine_kernel(const unsigned short* __restrict__ ctxpb,
                                                      const float* __restrict__ rsbuf,
                                                      unsigned short* __restrict__ ctxb){
    int e = blockIdx.x * 256 + threadIdx.x;     // one ushort4 per thread
    int row = e >> 8;
    int c4 = (e & 255) * 4;
    int h = c4 >> 6;
    float l = rsbuf[(size_t)row * 16 + h] + rsbuf[((size_t)4096 + row) * 16 + h];
    ushort4 a  = *(const ushort4*)&ctxpb[(size_t)row * 1024 + c4];
    ushort4 b2 = *(const ushort4*)&ctxpb[(size_t)4096 * 1024 + (size_t)row * 1024 + c4];
    float inv = 1.f / l;
    uint2 o;
    o.x = pkbf((bf2f(a.x) + bf2f(b2.x)) * inv, (bf2f(a.y) + bf2f(b2.y)) * inv);
    o.y = pkbf((bf2f(a.z) + bf2f(b2.z)) * inv, (bf2f(a.w) + bf2f(b2.w)) * inv);
    *(uint2*)&ctxb[(size_t)row * 1024 + c4] = o;
}

extern "C" void kernel_launch(void* const* d_in, const int* in_sizes, int n_in,
                              void* d_out, int out_size, void* d_ws, size_t ws_size,
                              hipStream_t stream) {
    const float* hs       = (const float*)d_in[0];
    const float* Wq       = (const float*)d_in[1];
    const float* Wk       = (const float*)d_in[2];
    const float* Wv       = (const float*)d_in[3];
    const float* Wo       = (const float*)d_in[4];
    const float* rel_bias = (const float*)d_in[5];
    float* out = (float*)d_out;

    char* ws = (char*)d_ws;
    float* biasT          = (float*)ws;           ws += 262144;      // 16*4095*4 (+pad)
    unsigned short* hsb   = (unsigned short*)ws;  ws += 8388608;     // 4096x1024 bf16
    unsigned short* WT    = (unsigned short*)ws;  ws += 6291456;     // [Wq^T|Wk^T|Wv^T] 3072x1024
    unsigned short* WoT   = (unsigned short*)ws;  ws += 2097152;     // 1024x1024 bf16
    unsigned short* qkvb  = (unsigned short*)ws;  ws += 25165824;    // 4096x3072 bf16 (Q|K|V)
    unsigned short* Vtg   = (unsigned short*)ws;  ws += 8388608;     // 2048x2048 bf16
    unsigned short* ctxb  = (unsigned short*)ws;  ws += 8388608;     // 4096x1024 bf16
    unsigned short* ctxpb = (unsigned short*)ws;  ws += 16777216;    // 2 x 4096x1024 bf16
    float* rsbuf          = (float*)ws;                              // 2 x 4096x16 fp32

    prep_kernel<<<dim3(32, 32, 5), 256, 0, stream>>>(
        hs, hsb, Wq, Wk, Wv, Wo,
        WT, WT + 1024 * 1024, WT + 2 * 1024 * 1024, WoT, rel_bias, biasT);

    // Q|K|V projection, BM=64 -> 1536 blocks (6/CU) for latency hiding
    gemm_bt_kernel<1, 64><<<dim3(24, 64), 256, 0, stream>>>(hsb, WT, nullptr, qkvb, 1024, 3072);
    // V transpose -> Vt[b*1024 + d][2048]
    vtrans_kernel<<<dim3(16, 32, 2), 256, 0, stream>>>(qkvb, Vtg);
    // attention, split-S x2
    flash10_kernel<<<dim3(S_LEN / 128, NH, 4), 256, 0, stream>>>(qkvb, Vtg, biasT, rel_bias, ctxpb, rsbuf);
    // combine partials -> bf16 ctx
    combine_kernel<<<4096, 256, 0, stream>>>(ctxpb, rsbuf, ctxb);
    // output projection -> fp32 (BM=64: 512 blocks, 2/CU)
    gemm_bt_kernel<0, 64><<<dim3(8, 64), 256, 0, stream>>>(ctxb, WoT, out, nullptr, 1024, 1024);
}